// Round 1
// baseline (259.680 us; speedup 1.0000x reference)
//
#include <hip/hip_runtime.h>

#define BGR 8
#define VG  20000
#define NK  128
#define ND  128

typedef float f32x4 __attribute__((ext_vector_type(4)));
typedef short bf16x8 __attribute__((ext_vector_type(8)));

// two fp32 -> packed 2x bf16 (RNE) in one instruction
__device__ __forceinline__ unsigned cvtpk(float a, float b) {
    unsigned r;
    asm("v_cvt_pk_bf16_f32 %0, %1, %2" : "=v"(r) : "v"(a), "v"(b));
    return r;
}

// ---------------------------------------------------------------------------
// Kernel 1: xsT[g][d][k] += sum_v (m*x)[v,d] * E[v,k]   (per 320-v chunk)
// Swapped MFMA roles vs old version: A = x-tile (rows=d), B = E-tile (cols=k),
// so the accumulator is natively [d][k] -> coalesced atomics, and k_out's
// B-operand (Yt[d][k]) needs no further transpose.
// Staging: thread owns cols (cc, cc+64) x 8 consecutive v -> coalesced dword
// loads, cvt_pk conversion, ds_write_b128 into [col][v] tiles (S1=40 gives a
// perfect 32-bank tiling for the 64-lane b128 write AND 2-way-free b128 reads).
// Register prefetch of round r+1 is issued before the MFMA phase.
// ---------------------------------------------------------------------------
#define VC 320
#define S1 40

__global__ __launch_bounds__(256) void k_spec(const float* __restrict__ x,
                                              const float* __restrict__ mass,
                                              const float* __restrict__ evecs,
                                              float* __restrict__ xsT) {
    const int g     = blockIdx.y;
    const int chunk = blockIdx.x;
    const int v0    = chunk * VC;
    const int nv    = (VG - v0 < VC) ? (VG - v0) : VC;   // 320 or 160, both %32==0
    const int rounds = nv >> 5;

    const float* xg = x     + (size_t)g * VG * ND;
    const float* eg = evecs + (size_t)g * VG * NK;
    const float* mg = mass  + (size_t)g * VG;

    __shared__ short Et[NK * S1];  // [k][v]  (B operand: output cols)
    __shared__ short Xt[ND * S1];  // [d][v]  (A operand: output rows)

    const int tid = threadIdx.x;
    const int l   = tid & 63;
    const int w   = tid >> 6;
    const int lo  = l & 15, hi = l >> 4;
    const int r0  = (w & 1) * 64, c0 = (w >> 1) * 64;

    const int cc = l;   // column owned by this lane (and cc+64)
    const int oc = w;   // v-octet: rows oc*8 .. oc*8+7 of the 32-v round

    float eA[8], eB[8], xA[8], xB[8], mm[8];

    auto loadr = [&](int r) {
        const int vb = v0 + r * 32 + oc * 8;
#pragma unroll
        for (int q = 0; q < 8; ++q) {
            const size_t re = (size_t)(vb + q) * NK;
            const size_t rx = (size_t)(vb + q) * ND;
            eA[q] = eg[re + cc];  eB[q] = eg[re + cc + 64];
            xA[q] = xg[rx + cc];  xB[q] = xg[rx + cc + 64];
            mm[q] = mg[vb + q];
        }
    };

    f32x4 acc[4][4] = {};
    loadr(0);

    for (int r = 0; r < rounds; ++r) {
        // pack current regs -> LDS (v-ascending within each b128)
        uint4 u;
        u.x = cvtpk(eA[0], eA[1]); u.y = cvtpk(eA[2], eA[3]);
        u.z = cvtpk(eA[4], eA[5]); u.w = cvtpk(eA[6], eA[7]);
        *(uint4*)(Et + cc * S1 + oc * 8) = u;
        u.x = cvtpk(eB[0], eB[1]); u.y = cvtpk(eB[2], eB[3]);
        u.z = cvtpk(eB[4], eB[5]); u.w = cvtpk(eB[6], eB[7]);
        *(uint4*)(Et + (cc + 64) * S1 + oc * 8) = u;
        u.x = cvtpk(xA[0] * mm[0], xA[1] * mm[1]); u.y = cvtpk(xA[2] * mm[2], xA[3] * mm[3]);
        u.z = cvtpk(xA[4] * mm[4], xA[5] * mm[5]); u.w = cvtpk(xA[6] * mm[6], xA[7] * mm[7]);
        *(uint4*)(Xt + cc * S1 + oc * 8) = u;
        u.x = cvtpk(xB[0] * mm[0], xB[1] * mm[1]); u.y = cvtpk(xB[2] * mm[2], xB[3] * mm[3]);
        u.z = cvtpk(xB[4] * mm[4], xB[5] * mm[5]); u.w = cvtpk(xB[6] * mm[6], xB[7] * mm[7]);
        *(uint4*)(Xt + (cc + 64) * S1 + oc * 8) = u;

        // prefetch next round while this round's LDS is consumed
        if (r + 1 < rounds) loadr(r + 1);
        __syncthreads();

        bf16x8 ax[4], be[4];
#pragma unroll
        for (int i = 0; i < 4; ++i)
            ax[i] = *(const bf16x8*)(Xt + (r0 + 16 * i + lo) * S1 + hi * 8);
#pragma unroll
        for (int j = 0; j < 4; ++j)
            be[j] = *(const bf16x8*)(Et + (c0 + 16 * j + lo) * S1 + hi * 8);
#pragma unroll
        for (int i = 0; i < 4; ++i)
#pragma unroll
            for (int j = 0; j < 4; ++j)
                acc[i][j] = __builtin_amdgcn_mfma_f32_16x16x32_bf16(ax[i], be[j], acc[i][j], 0, 0, 0);
        __syncthreads();
    }

    // epilogue: C row = d (r0+16i+hi*4+t), col = k (c0+16j+lo) -> xsT[d][k]
    float* og = xsT + (size_t)g * ND * NK;
#pragma unroll
    for (int i = 0; i < 4; ++i)
#pragma unroll
        for (int j = 0; j < 4; ++j)
#pragma unroll
            for (int t = 0; t < 4; ++t) {
                const int dd = r0 + 16 * i + hi * 4 + t;
                const int kk = c0 + 16 * j + lo;
                atomicAdd(og + dd * NK + kk, acc[i][j][t]);
            }
}

// ---------------------------------------------------------------------------
// Kernel 2: Yt[g][d][k] = bf16( exp(-evals[g,k]*max(t[d],1e-8)) * xsT[g][d][k] )
// vectorized: 4 k per thread, float4 in, uint2 (4x bf16) out
// ---------------------------------------------------------------------------
__global__ __launch_bounds__(256) void k_coef(const float* __restrict__ xsT,
                                              const float* __restrict__ evals,
                                              const float* __restrict__ dt,
                                              short* __restrict__ Yt) {
    const int q  = blockIdx.x * 256 + threadIdx.x;  // 0 .. 8*128*32-1
    const int g  = q >> 12;
    const int d  = (q >> 5) & 127;
    const int k4 = (q & 31) << 2;
    const float t = fmaxf(dt[d], 1e-8f);
    const float4 lam = *(const float4*)(evals + g * NK + k4);
    const float4 v   = *(const float4*)(xsT + (size_t)g * ND * NK + d * NK + k4);
    uint2 r;
    r.x = cvtpk(__expf(-lam.x * t) * v.x, __expf(-lam.y * t) * v.y);
    r.y = cvtpk(__expf(-lam.z * t) * v.z, __expf(-lam.w * t) * v.w);
    *(uint2*)(Yt + (size_t)g * ND * NK + d * NK + k4) = r;
}

// ---------------------------------------------------------------------------
// Kernel 3: out[v,d] = sum_k E[v,k] * Yt[g][d][k]
// Both LDS tiles use the st-style XOR swizzle (8-short group ^= row&7):
// the old S2=128 linear layout made every ds_read_b128 a 16-way bank conflict
// (row stride 64 dwords == 0 mod 32). Swizzled reads are a perfect bank tiling.
// ---------------------------------------------------------------------------
__global__ __launch_bounds__(256) void k_out(const float* __restrict__ evecs,
                                             const short* __restrict__ Yt,
                                             float* __restrict__ out) {
    const int g     = blockIdx.y;
    const int chunk = blockIdx.x;               // 157 chunks: 156 full + 32-row tail
    const int v0    = chunk * 128;
    const int rows  = (VG - v0 < 128) ? (VG - v0) : 128;

    const float* eg = evecs + (size_t)g * VG * NK;
    float*       og = out   + (size_t)g * VG * ND;
    const short* yg = Yt    + (size_t)g * ND * NK;

    __shared__ short As[128 * 128];  // E tile  [v][k] bf16, swizzled
    __shared__ short Bs[128 * 128];  // Yt tile [d][k] bf16, swizzled

    const int tid = threadIdx.x;

#pragma unroll
    for (int it = 0; it < 16; ++it) {
        const int id = it * 256 + tid;
        const int v  = id >> 5;                  // row 0..127
        const int c4 = (id & 31) << 2;           // col 0..124 step 4
        const int vc = v < rows ? v : rows - 1;  // clamp tail OOB reads
        const float4 e4 = *(const float4*)(eg + (size_t)(v0 + vc) * NK + c4);
        uint2 p; p.x = cvtpk(e4.x, e4.y); p.y = cvtpk(e4.z, e4.w);
        *(uint2*)(As + v * 128 + (((c4 >> 3) ^ (v & 7)) << 3) + (c4 & 7)) = p;
        if (it < 8) {
            const int s16 = it * 256 + tid;      // 16B slot 0..2047
            const int rr  = s16 >> 4, gq = s16 & 15;
            *(uint4*)(Bs + rr * 128 + ((gq ^ (rr & 7)) << 3)) =
                *(const uint4*)(yg + s16 * 8);
        }
    }
    __syncthreads();

    const int l  = tid & 63;
    const int w  = tid >> 6;
    const int lo = l & 15, hi = l >> 4;
    const int r0 = (w & 1) * 64, c0 = (w >> 1) * 64;

    f32x4 acc[4][4] = {};
#pragma unroll
    for (int ks = 0; ks < 4; ++ks) {
        bf16x8 af[4], bv[4];
#pragma unroll
        for (int i = 0; i < 4; ++i) {
            const int R = r0 + 16 * i + lo;
            af[i] = *(const bf16x8*)(As + R * 128 + ((((ks << 2) + hi) ^ (R & 7)) << 3));
        }
#pragma unroll
        for (int j = 0; j < 4; ++j) {
            const int Dd = c0 + 16 * j + lo;
            bv[j] = *(const bf16x8*)(Bs + Dd * 128 + ((((ks << 2) + hi) ^ (Dd & 7)) << 3));
        }
#pragma unroll
        for (int i = 0; i < 4; ++i)
#pragma unroll
            for (int j = 0; j < 4; ++j)
                acc[i][j] = __builtin_amdgcn_mfma_f32_16x16x32_bf16(af[i], bv[j], acc[i][j], 0, 0, 0);
    }

#pragma unroll
    for (int i = 0; i < 4; ++i)
#pragma unroll
        for (int j = 0; j < 4; ++j)
#pragma unroll
            for (int t = 0; t < 4; ++t) {
                const int vv = r0 + 16 * i + hi * 4 + t;
                if (vv < rows)
                    og[(size_t)(v0 + vv) * ND + c0 + 16 * j + lo] = acc[i][j][t];
            }
}

extern "C" void kernel_launch(void* const* d_in, const int* in_sizes, int n_in,
                              void* d_out, int out_size, void* d_ws, size_t ws_size,
                              hipStream_t stream) {
    const float* x     = (const float*)d_in[0];
    const float* mass  = (const float*)d_in[1];
    const float* evals = (const float*)d_in[2];
    const float* evecs = (const float*)d_in[3];
    const float* dt    = (const float*)d_in[4];
    // d_in[5] = batch (unused: equal-sized graphs), d_in[6] = bs (compile-time 8)
    float* out = (float*)d_out;

    float* xsT = (float*)d_ws;                                        // 8*128*128 fp32 = 512KB
    short* Yt  = (short*)((char*)d_ws + (size_t)BGR * ND * NK * 4);   // 8*128*128 bf16 = 256KB

    hipMemsetAsync(d_ws, 0, (size_t)BGR * ND * NK * sizeof(float), stream);

    k_spec<<<dim3((VG + VC - 1) / VC, BGR), 256, 0, stream>>>(x, mass, evecs, xsT);
    k_coef<<<(BGR * ND * NK / 4) / 256, 256, 0, stream>>>(xsT, evals, dt, Yt);
    k_out<<<dim3((VG + 127) / 128, BGR), 256, 0, stream>>>(evecs, Yt, out);
}

// Round 2
// 252.364 us; speedup vs baseline: 1.0290x; 1.0290x over previous
//
#include <hip/hip_runtime.h>

#define BGR 8
#define VG  20000
#define NK  128
#define ND  128

typedef float f32x4 __attribute__((ext_vector_type(4)));
typedef short bf16x8 __attribute__((ext_vector_type(8)));

// two fp32 -> packed 2x bf16 (RNE) in one instruction
__device__ __forceinline__ unsigned cvtpk(float a, float b) {
    unsigned r;
    asm("v_cvt_pk_bf16_f32 %0, %1, %2" : "=v"(r) : "v"(a), "v"(b));
    return r;
}

// fp32 -> bf16 bits, round-to-nearest-even (scalar, for k_coef)
__device__ __forceinline__ short bf16r(float f) {
    union { float f; unsigned u; } c; c.f = f;
    unsigned r = (c.u + 0x7FFFu + ((c.u >> 16) & 1u)) >> 16;
    return (short)r;
}

// ---------------------------------------------------------------------------
// Kernel 1: partial[bid][d][k] = sum_{v in 160-chunk} (m*x)[v,d] * E[v,k]
// NO atomics: each block streams its private 64KB fp32 partial into scratch
// (the output buffer, reused as scratch -- k_out fully overwrites it later).
// Previous version: 8.25M atomicAdds -> 32MB of fabric RMW traffic that
// serialized the memory system (MfmaUtil 2%, VALU 4%, HBM 16%, all idle).
// VC=160 (was 320) -> 1000 blocks, ~4 blocks/CU (occupancy was grid-capped).
// XCD pin: g = bid&7. 125*160 = 20000 exactly -> no tails anywhere.
// ---------------------------------------------------------------------------
#define VC  160
#define S1  40
#define NCH (VG / VC)   // 125

__global__ __launch_bounds__(256) void k_spec(const float* __restrict__ x,
                                              const float* __restrict__ mass,
                                              const float* __restrict__ evecs,
                                              float* __restrict__ scr) {
    const int bid   = blockIdx.x;
    const int g     = bid & 7;
    const int chunk = bid >> 3;
    const int v0    = chunk * VC;

    const float* xg = x     + (size_t)g * VG * ND;
    const float* eg = evecs + (size_t)g * VG * NK;
    const float* mg = mass  + (size_t)g * VG;

    __shared__ short Et[NK * S1];  // [k][v]  (B operand: output cols)
    __shared__ short Xt[ND * S1];  // [d][v]  (A operand: output rows)

    const int tid = threadIdx.x;
    const int l   = tid & 63;
    const int w   = tid >> 6;
    const int lo  = l & 15, hi = l >> 4;
    const int r0  = (w & 1) * 64, c0 = (w >> 1) * 64;

    const int cc = l;   // column owned by this lane (and cc+64)
    const int oc = w;   // v-octet: rows oc*8 .. oc*8+7 of the 32-v round

    float eA[8], eB[8], xA[8], xB[8], mm[8];

    auto loadr = [&](int r) {
        const int vb = v0 + r * 32 + oc * 8;
#pragma unroll
        for (int q = 0; q < 8; ++q) {
            const size_t re = (size_t)(vb + q) * NK;
            const size_t rx = (size_t)(vb + q) * ND;
            eA[q] = eg[re + cc];  eB[q] = eg[re + cc + 64];
            xA[q] = xg[rx + cc];  xB[q] = xg[rx + cc + 64];
            mm[q] = mg[vb + q];
        }
    };

    f32x4 acc[4][4] = {};
    loadr(0);

#pragma unroll
    for (int r = 0; r < VC / 32; ++r) {
        // pack current regs -> LDS (v-ascending within each b128)
        uint4 u;
        u.x = cvtpk(eA[0], eA[1]); u.y = cvtpk(eA[2], eA[3]);
        u.z = cvtpk(eA[4], eA[5]); u.w = cvtpk(eA[6], eA[7]);
        *(uint4*)(Et + cc * S1 + oc * 8) = u;
        u.x = cvtpk(eB[0], eB[1]); u.y = cvtpk(eB[2], eB[3]);
        u.z = cvtpk(eB[4], eB[5]); u.w = cvtpk(eB[6], eB[7]);
        *(uint4*)(Et + (cc + 64) * S1 + oc * 8) = u;
        u.x = cvtpk(xA[0] * mm[0], xA[1] * mm[1]); u.y = cvtpk(xA[2] * mm[2], xA[3] * mm[3]);
        u.z = cvtpk(xA[4] * mm[4], xA[5] * mm[5]); u.w = cvtpk(xA[6] * mm[6], xA[7] * mm[7]);
        *(uint4*)(Xt + cc * S1 + oc * 8) = u;
        u.x = cvtpk(xB[0] * mm[0], xB[1] * mm[1]); u.y = cvtpk(xB[2] * mm[2], xB[3] * mm[3]);
        u.z = cvtpk(xB[4] * mm[4], xB[5] * mm[5]); u.w = cvtpk(xB[6] * mm[6], xB[7] * mm[7]);
        *(uint4*)(Xt + (cc + 64) * S1 + oc * 8) = u;

        // prefetch next round while this round's LDS is consumed
        if (r + 1 < VC / 32) loadr(r + 1);
        __syncthreads();

        bf16x8 ax[4], be[4];
#pragma unroll
        for (int i = 0; i < 4; ++i)
            ax[i] = *(const bf16x8*)(Xt + (r0 + 16 * i + lo) * S1 + hi * 8);
#pragma unroll
        for (int j = 0; j < 4; ++j)
            be[j] = *(const bf16x8*)(Et + (c0 + 16 * j + lo) * S1 + hi * 8);
#pragma unroll
        for (int i = 0; i < 4; ++i)
#pragma unroll
            for (int j = 0; j < 4; ++j)
                acc[i][j] = __builtin_amdgcn_mfma_f32_16x16x32_bf16(ax[i], be[j], acc[i][j], 0, 0, 0);
        __syncthreads();
    }

    // epilogue: plain streamed stores of the private partial tile [d][k]
    float* sg = scr + (size_t)bid * ND * NK;
#pragma unroll
    for (int i = 0; i < 4; ++i)
#pragma unroll
        for (int j = 0; j < 4; ++j)
#pragma unroll
            for (int t = 0; t < 4; ++t) {
                const int dd = r0 + 16 * i + hi * 4 + t;
                const int kk = c0 + 16 * j + lo;
                sg[dd * NK + kk] = acc[i][j][t];
            }
}

// ---------------------------------------------------------------------------
// Kernel 2: reduce 125 partials + apply exp(-lambda*t), write bf16 Yt[g][d][k]
// one thread per output element; partials are LLC-hot (just written)
// ---------------------------------------------------------------------------
__global__ __launch_bounds__(256) void k_coef(const float* __restrict__ scr,
                                              const float* __restrict__ evals,
                                              const float* __restrict__ dt,
                                              short* __restrict__ Yt) {
    const int q   = blockIdx.x * 256 + threadIdx.x;  // 0 .. 8*128*128-1
    const int g   = q >> 14;
    const int rem = q & 16383;
    const int d   = rem >> 7;
    const int k   = rem & 127;
    const float* p = scr + (size_t)g * ND * NK + rem;
    float s = 0.f;
#pragma unroll 25
    for (int c = 0; c < NCH; ++c)
        s += p[(size_t)c * 8 * ND * NK];
    const float t = fmaxf(dt[d], 1e-8f);
    Yt[q] = bf16r(__expf(-evals[g * NK + k] * t) * s);
}

// ---------------------------------------------------------------------------
// Kernel 3: out[v,d] = sum_k E[v,k] * Yt[g][d][k]
// Persistent: 64 blocks per graph; Yt tile (32KB) staged ONCE per block
// (was re-staged by all 157 chunks), then loop over 64-row evec tiles with
// double-buffered LDS: global loads for tile t+64 issued before the barrier,
// MFMA on tile t, cvt+ds_write after. Same verified XOR swizzle as before.
// ---------------------------------------------------------------------------
#define TV  64
#define NT  ((VG + TV - 1) / TV)   // 313 (312 full + one 32-row tail)
#define NSL 64                     // slots per graph

__global__ __launch_bounds__(256) void k_out(const float* __restrict__ evecs,
                                             const short* __restrict__ Yt,
                                             float* __restrict__ out) {
    const int bid  = blockIdx.x;   // 512 = 64 slots x 8 graphs
    const int g    = bid & 7;
    const int slot = bid >> 3;

    const float* eg = evecs + (size_t)g * VG * NK;
    float*       og = out   + (size_t)g * VG * ND;
    const short* yg = Yt    + (size_t)g * ND * NK;

    __shared__ short Bs[128 * 128];     // Yt [d][k] swizzled, staged once
    __shared__ short As[2][TV * 128];   // E tiles [v][k] swizzled, dbuf

    const int tid = threadIdx.x;

    // stage Bs once (pure 16B-granule copy, swizzled)
#pragma unroll
    for (int it = 0; it < 8; ++it) {
        const int s16 = it * 256 + tid;
        const int rr  = s16 >> 4, gq = s16 & 15;
        *(uint4*)(Bs + rr * 128 + ((gq ^ (rr & 7)) << 3)) =
            *(const uint4*)(yg + s16 * 8);
    }

    const int vrow = tid >> 2;   // 0..63: row within tile
    const int q4   = tid & 3;    // column quarter (32 cols)

    float4 ld[8];
    auto load_tile = [&](int t) {
        const int tv0  = t * TV;
        const int rows = (VG - tv0 < TV) ? (VG - tv0) : TV;
        const int vc   = vrow < rows ? vrow : rows - 1;  // clamp tail OOB
        const float* src = eg + (size_t)(tv0 + vc) * NK + q4 * 32;
#pragma unroll
        for (int f = 0; f < 8; ++f) ld[f] = *(const float4*)(src + 4 * f);
    };
    auto write_tile = [&](int buf) {
        short* A = As[buf];
#pragma unroll
        for (int h = 0; h < 4; ++h) {
            uint4 u;
            u.x = cvtpk(ld[2 * h].x, ld[2 * h].y);
            u.y = cvtpk(ld[2 * h].z, ld[2 * h].w);
            u.z = cvtpk(ld[2 * h + 1].x, ld[2 * h + 1].y);
            u.w = cvtpk(ld[2 * h + 1].z, ld[2 * h + 1].w);
            const int g8 = q4 * 4 + h;
            *(uint4*)(A + vrow * 128 + ((g8 ^ (vrow & 7)) << 3)) = u;
        }
    };

    const int l  = tid & 63;
    const int w  = tid >> 6;
    const int lo = l & 15, hi = l >> 4;
    const int r0 = (w & 1) * 32, c0 = (w >> 1) * 64;  // 32x64 per wave

    int t = slot;
    load_tile(t);
    write_tile(0);
    int cur = 0;

    for (; t < NT; t += NSL) {
        const int tn = t + NSL;
        if (tn < NT) load_tile(tn);
        __syncthreads();   // As[cur] (and Bs on first iter) visible

        f32x4 acc[2][4] = {};
        const short* A = As[cur];
#pragma unroll
        for (int ks = 0; ks < 4; ++ks) {
            bf16x8 af[2], bv[4];
#pragma unroll
            for (int i = 0; i < 2; ++i) {
                const int R = r0 + 16 * i + lo;
                af[i] = *(const bf16x8*)(A + R * 128 + ((((ks << 2) + hi) ^ (R & 7)) << 3));
            }
#pragma unroll
            for (int j = 0; j < 4; ++j) {
                const int Dd = c0 + 16 * j + lo;
                bv[j] = *(const bf16x8*)(Bs + Dd * 128 + ((((ks << 2) + hi) ^ (Dd & 7)) << 3));
            }
#pragma unroll
            for (int i = 0; i < 2; ++i)
#pragma unroll
                for (int j = 0; j < 4; ++j)
                    acc[i][j] = __builtin_amdgcn_mfma_f32_16x16x32_bf16(af[i], bv[j], acc[i][j], 0, 0, 0);
        }

        const int tv0  = t * TV;
        const int rows = (VG - tv0 < TV) ? (VG - tv0) : TV;
#pragma unroll
        for (int i = 0; i < 2; ++i)
#pragma unroll
            for (int j = 0; j < 4; ++j)
#pragma unroll
                for (int u = 0; u < 4; ++u) {
                    const int vv = r0 + 16 * i + hi * 4 + u;
                    if (vv < rows)
                        og[(size_t)(tv0 + vv) * ND + c0 + 16 * j + lo] = acc[i][j][u];
                }

        // write next tile into the other buffer (safe: all waves passed the
        // barrier above, so their reads of As[cur^1] from iter t-NSL are done)
        if (tn < NT) write_tile(cur ^ 1);
        cur ^= 1;
    }
}

extern "C" void kernel_launch(void* const* d_in, const int* in_sizes, int n_in,
                              void* d_out, int out_size, void* d_ws, size_t ws_size,
                              hipStream_t stream) {
    const float* x     = (const float*)d_in[0];
    const float* mass  = (const float*)d_in[1];
    const float* evals = (const float*)d_in[2];
    const float* evecs = (const float*)d_in[3];
    const float* dt    = (const float*)d_in[4];
    // d_in[5] = batch (unused: equal-sized graphs), d_in[6] = bs (compile-time 8)
    float* out = (float*)d_out;

    // partials live in the OUTPUT buffer (64MB <= 82MB), fully overwritten by
    // k_out afterwards; Yt lives in the workspace (256KB)
    float* scr = out;
    short* Yt  = (short*)d_ws;

    k_spec<<<NCH * BGR, 256, 0, stream>>>(x, mass, evecs, scr);
    k_coef<<<(BGR * ND * NK) / 256, 256, 0, stream>>>(scr, evals, dt, Yt);
    k_out<<<NSL * BGR, 256, 0, stream>>>(evecs, Yt, out);
}

// Round 3
// 251.497 us; speedup vs baseline: 1.0325x; 1.0034x over previous
//
#include <hip/hip_runtime.h>

#define BGR 8
#define VG  20000
#define NK  128
#define ND  128

typedef float f32x4 __attribute__((ext_vector_type(4)));
typedef short bf16x8 __attribute__((ext_vector_type(8)));

// two fp32 -> packed 2x bf16 (RNE) in one instruction
__device__ __forceinline__ unsigned cvtpk(float a, float b) {
    unsigned r;
    asm("v_cvt_pk_bf16_f32 %0, %1, %2" : "=v"(r) : "v"(a), "v"(b));
    return r;
}

// fp32 -> bf16 bits, round-to-nearest-even (scalar, for k_coef)
__device__ __forceinline__ short bf16r(float f) {
    union { float f; unsigned u; } c; c.f = f;
    unsigned r = (c.u + 0x7FFFu + ((c.u >> 16) & 1u)) >> 16;
    return (short)r;
}

// ---------------------------------------------------------------------------
// Kernel 1: partial[bid][d][k] = sum_{v in 160-chunk} (m*x)[v,d] * E[v,k]
// Register ping-pong + issue-ahead: loads for round r+1 are issued BEFORE the
// pack of round r, so the pack's counted vmcnt keeps the next round in flight
// (previous version had zero bytes in flight during wait+pack -> 50% memory
// duty cycle, 1.9 TB/s). float2 loads (lane owns cols 2l, 2l+1), mass staged
// once in LDS. v-octet XOR swizzle (slot = oc ^ ((col>>3)&3)) keeps the
// ds_write_b128 at 4-way (col-pair layout would otherwise be 8-way) while
// preserving 16B alignment; same swizzle applied on fragment reads.
// ---------------------------------------------------------------------------
#define VC  160
#define S1  40
#define NCH (VG / VC)   // 125

__global__ __launch_bounds__(256) void k_spec(const float* __restrict__ x,
                                              const float* __restrict__ mass,
                                              const float* __restrict__ evecs,
                                              float* __restrict__ scr) {
    const int bid   = blockIdx.x;
    const int g     = bid & 7;        // XCD pin
    const int chunk = bid >> 3;
    const int v0    = chunk * VC;

    const float* xg = x     + (size_t)g * VG * ND;
    const float* eg = evecs + (size_t)g * VG * NK;
    const float* mg = mass  + (size_t)g * VG;

    __shared__ short Et[NK * S1];  // [k][v] bf16, octet-swizzled
    __shared__ short Xt[ND * S1];  // [d][v] bf16, octet-swizzled
    __shared__ float Ms[VC];

    const int tid = threadIdx.x;
    const int l   = tid & 63;
    const int w   = tid >> 6;
    const int lo  = l & 15, hi = l >> 4;
    const int r0  = (w & 1) * 64, c0 = (w >> 1) * 64;
    const int oc  = w;                       // v-octet owned by this wave
    const int C0  = 2 * l;                   // col pair owned by this lane
    const int sw  = ((oc ^ ((l >> 2) & 3)) << 3);  // swizzled octet slot (shorts)

    if (tid < VC) Ms[tid] = mg[v0 + tid];

    float2 e0[8], x0[8], e1[8], x1[8];

#define ISSUE_SPEC(EB, XB, r) do {                                          \
    const int vb_ = v0 + (r) * 32 + oc * 8;                                 \
    _Pragma("unroll")                                                       \
    for (int q = 0; q < 8; ++q) {                                           \
        EB[q] = *(const float2*)(eg + (size_t)(vb_ + q) * NK + C0);         \
        XB[q] = *(const float2*)(xg + (size_t)(vb_ + q) * ND + C0);         \
    } } while (0)

#define PACK_SPEC(EB, XB, r) do {                                           \
    const int mb_ = (r) * 32 + oc * 8;                                      \
    float m_[8];                                                            \
    _Pragma("unroll")                                                       \
    for (int q = 0; q < 8; ++q) m_[q] = Ms[mb_ + q];                        \
    uint4 u_;                                                               \
    u_.x = cvtpk(EB[0].x, EB[1].x); u_.y = cvtpk(EB[2].x, EB[3].x);         \
    u_.z = cvtpk(EB[4].x, EB[5].x); u_.w = cvtpk(EB[6].x, EB[7].x);         \
    *(uint4*)(Et + C0 * S1 + sw) = u_;                                      \
    u_.x = cvtpk(EB[0].y, EB[1].y); u_.y = cvtpk(EB[2].y, EB[3].y);         \
    u_.z = cvtpk(EB[4].y, EB[5].y); u_.w = cvtpk(EB[6].y, EB[7].y);         \
    *(uint4*)(Et + (C0 + 1) * S1 + sw) = u_;                                \
    u_.x = cvtpk(XB[0].x * m_[0], XB[1].x * m_[1]);                         \
    u_.y = cvtpk(XB[2].x * m_[2], XB[3].x * m_[3]);                         \
    u_.z = cvtpk(XB[4].x * m_[4], XB[5].x * m_[5]);                         \
    u_.w = cvtpk(XB[6].x * m_[6], XB[7].x * m_[7]);                         \
    *(uint4*)(Xt + C0 * S1 + sw) = u_;                                      \
    u_.x = cvtpk(XB[0].y * m_[0], XB[1].y * m_[1]);                         \
    u_.y = cvtpk(XB[2].y * m_[2], XB[3].y * m_[3]);                         \
    u_.z = cvtpk(XB[4].y * m_[4], XB[5].y * m_[5]);                         \
    u_.w = cvtpk(XB[6].y * m_[6], XB[7].y * m_[7]);                         \
    *(uint4*)(Xt + (C0 + 1) * S1 + sw) = u_;                                \
    } while (0)

#define MFMA_SPEC() do {                                                    \
    bf16x8 ax_[4], be_[4];                                                  \
    _Pragma("unroll")                                                       \
    for (int i = 0; i < 4; ++i) {                                           \
        const int R_ = r0 + 16 * i + lo;                                    \
        ax_[i] = *(const bf16x8*)(Xt + R_ * S1 + ((hi ^ ((R_ >> 3) & 3)) << 3)); } \
    _Pragma("unroll")                                                       \
    for (int j = 0; j < 4; ++j) {                                           \
        const int R_ = c0 + 16 * j + lo;                                    \
        be_[j] = *(const bf16x8*)(Et + R_ * S1 + ((hi ^ ((R_ >> 3) & 3)) << 3)); } \
    _Pragma("unroll")                                                       \
    for (int i = 0; i < 4; ++i)                                             \
    _Pragma("unroll")                                                       \
    for (int j = 0; j < 4; ++j)                                             \
        acc[i][j] = __builtin_amdgcn_mfma_f32_16x16x32_bf16(ax_[i], be_[j], acc[i][j], 0, 0, 0); \
    } while (0)

    f32x4 acc[4][4] = {};

    ISSUE_SPEC(e0, x0, 0);
    __syncthreads();   // Ms visible before first pack

    ISSUE_SPEC(e1, x1, 1); PACK_SPEC(e0, x0, 0); __syncthreads(); MFMA_SPEC(); __syncthreads();
    ISSUE_SPEC(e0, x0, 2); PACK_SPEC(e1, x1, 1); __syncthreads(); MFMA_SPEC(); __syncthreads();
    ISSUE_SPEC(e1, x1, 3); PACK_SPEC(e0, x0, 2); __syncthreads(); MFMA_SPEC(); __syncthreads();
    ISSUE_SPEC(e0, x0, 4); PACK_SPEC(e1, x1, 3); __syncthreads(); MFMA_SPEC(); __syncthreads();
    PACK_SPEC(e0, x0, 4); __syncthreads(); MFMA_SPEC();

    // epilogue: streamed stores of the private partial tile [d][k]
    float* sg = scr + (size_t)bid * ND * NK;
#pragma unroll
    for (int i = 0; i < 4; ++i)
#pragma unroll
        for (int j = 0; j < 4; ++j)
#pragma unroll
            for (int t = 0; t < 4; ++t) {
                const int dd = r0 + 16 * i + hi * 4 + t;
                const int kk = c0 + 16 * j + lo;
                sg[dd * NK + kk] = acc[i][j][t];
            }
#undef ISSUE_SPEC
#undef PACK_SPEC
#undef MFMA_SPEC
}

// ---------------------------------------------------------------------------
// Kernel 2: reduce 125 partials + apply exp(-lambda*t), write bf16 Yt[g][d][k]
// XCD-pinned (g = bid&7): each XCD reduces the slabs its own k_spec blocks
// wrote -> L2-local reads instead of cross-XCD LLC.
// ---------------------------------------------------------------------------
__global__ __launch_bounds__(256) void k_coef(const float* __restrict__ scr,
                                              const float* __restrict__ evals,
                                              const float* __restrict__ dt,
                                              short* __restrict__ Yt) {
    const int bid = blockIdx.x;                       // 512
    const int g   = bid & 7;
    const int rem = (bid >> 3) * 256 + threadIdx.x;   // 0..16383
    const int d   = rem >> 7;
    const int k   = rem & 127;
    const float* p = scr + (size_t)g * ND * NK + rem;
    float s = 0.f;
#pragma unroll 25
    for (int c = 0; c < NCH; ++c)
        s += p[(size_t)c * 8 * ND * NK];
    const float t = fmaxf(dt[d], 1e-8f);
    Yt[(size_t)g * ND * NK + rem] = bf16r(__expf(-evals[g * NK + k] * t) * s);
}

// ---------------------------------------------------------------------------
// Kernel 3: out[v,d] = sum_k E[v,k] * Yt[g][d][k]
// Contiguous 320-row span per block (63 blocks/graph, XCD-pinned), 5 tiles of
// 64 rows, fully unrolled with uniform guards. 2-deep issue-ahead ping-pong:
// prologue issues Bs loads first (oldest), then tiles 0 and 1; each iteration
// issues tile t+2 before the MFMA and ds-writes tile t+1 after the stores, so
// counted vmcnt waits never drain the pipeline. Verified XOR swizzles kept.
// ---------------------------------------------------------------------------
#define TV    64
#define TPB   5
#define VSPAN (TV * TPB)                    // 320
#define NBLK  ((VG + VSPAN - 1) / VSPAN)    // 63

__global__ __launch_bounds__(256) void k_out(const float* __restrict__ evecs,
                                             const short* __restrict__ Yt,
                                             float* __restrict__ out) {
    const int bid    = blockIdx.x;          // 504 = 63 spans x 8 graphs
    const int g      = bid & 7;
    const int slot   = bid >> 3;
    const int v_base = slot * VSPAN;

    const float* eg = evecs + (size_t)g * VG * NK;
    float*       og = out   + (size_t)g * VG * ND;
    const short* yg = Yt    + (size_t)g * ND * NK;

    __shared__ short Bs[128 * 128];     // Yt [d][k] swizzled, staged once
    __shared__ short As[2][TV * 128];   // E tiles [v][k] swizzled, dbuf

    const int tid  = threadIdx.x;
    const int vrow = tid >> 2;   // 0..63: row within tile
    const int q4   = tid & 3;    // column quarter (32 cols)

    float4 ldA[8], ldB[8];

#define ISSUE_OUT(BUF, t) do {                                              \
    const int tv0_ = v_base + (t) * TV;                                     \
    if (tv0_ < VG) {                                                        \
        const int rows_ = (VG - tv0_ < TV) ? (VG - tv0_) : TV;              \
        const int vc_   = vrow < rows_ ? vrow : rows_ - 1;                  \
        const float* s_ = eg + (size_t)(tv0_ + vc_) * NK + q4 * 32;         \
        _Pragma("unroll")                                                   \
        for (int f = 0; f < 8; ++f) BUF[f] = *(const float4*)(s_ + 4 * f);  \
    } } while (0)

#define WRITE_OUT(BUF, t) do {                                              \
    if (v_base + (t) * TV < VG) {                                           \
        short* A_ = As[(t) & 1];                                            \
        _Pragma("unroll")                                                   \
        for (int h = 0; h < 4; ++h) {                                       \
            uint4 u_;                                                       \
            u_.x = cvtpk(BUF[2 * h].x, BUF[2 * h].y);                       \
            u_.y = cvtpk(BUF[2 * h].z, BUF[2 * h].w);                       \
            u_.z = cvtpk(BUF[2 * h + 1].x, BUF[2 * h + 1].y);               \
            u_.w = cvtpk(BUF[2 * h + 1].z, BUF[2 * h + 1].w);               \
            const int g8_ = q4 * 4 + h;                                     \
            *(uint4*)(A_ + vrow * 128 + ((g8_ ^ (vrow & 7)) << 3)) = u_;    \
        } } } while (0)

    // prologue: Bs global loads FIRST (oldest in vmcnt FIFO), then tiles 0,1
    uint4 bq[8];
#pragma unroll
    for (int it = 0; it < 8; ++it)
        bq[it] = *(const uint4*)(yg + (it * 256 + tid) * 8);
    ISSUE_OUT(ldA, 0);
    ISSUE_OUT(ldB, 1);
#pragma unroll
    for (int it = 0; it < 8; ++it) {
        const int s16 = it * 256 + tid;
        const int rr  = s16 >> 4, gq = s16 & 15;
        *(uint4*)(Bs + rr * 128 + ((gq ^ (rr & 7)) << 3)) = bq[it];
    }
    WRITE_OUT(ldA, 0);   // waits Bs+tile0 loads; tile1 stays in flight
    __syncthreads();

    const int l  = tid & 63;
    const int w  = tid >> 6;
    const int lo = l & 15, hi = l >> 4;
    const int r0 = (w & 1) * 32, c0 = (w >> 1) * 64;  // 32x64 per wave

#define MFMA_OUT(t) do {                                                    \
    const int tv0_ = v_base + (t) * TV;                                     \
    if (tv0_ < VG) {                                                        \
        const int rows_ = (VG - tv0_ < TV) ? (VG - tv0_) : TV;              \
        const short* A_ = As[(t) & 1];                                      \
        f32x4 acc[2][4] = {};                                               \
        _Pragma("unroll")                                                   \
        for (int ks = 0; ks < 4; ++ks) {                                    \
            bf16x8 af_[2], bv_[4];                                          \
            _Pragma("unroll")                                               \
            for (int i = 0; i < 2; ++i) {                                   \
                const int R_ = r0 + 16 * i + lo;                            \
                af_[i] = *(const bf16x8*)(A_ + R_ * 128 + ((((ks << 2) + hi) ^ (R_ & 7)) << 3)); } \
            _Pragma("unroll")                                               \
            for (int j = 0; j < 4; ++j) {                                   \
                const int D_ = c0 + 16 * j + lo;                            \
                bv_[j] = *(const bf16x8*)(Bs + D_ * 128 + ((((ks << 2) + hi) ^ (D_ & 7)) << 3)); } \
            _Pragma("unroll")                                               \
            for (int i = 0; i < 2; ++i)                                     \
            _Pragma("unroll")                                               \
            for (int j = 0; j < 4; ++j)                                     \
                acc[i][j] = __builtin_amdgcn_mfma_f32_16x16x32_bf16(af_[i], bv_[j], acc[i][j], 0, 0, 0); \
        }                                                                   \
        _Pragma("unroll")                                                   \
        for (int i = 0; i < 2; ++i)                                         \
        _Pragma("unroll")                                                   \
        for (int j = 0; j < 4; ++j)                                         \
        _Pragma("unroll")                                                   \
        for (int u = 0; u < 4; ++u) {                                       \
            const int vv_ = r0 + 16 * i + hi * 4 + u;                       \
            if (vv_ < rows_)                                                \
                og[(size_t)(tv0_ + vv_) * ND + c0 + 16 * j + lo] = acc[i][j][u]; \
        } } } while (0)

    // iter ti: issue tile ti+2 into the buffer freed last iter, compute tile
    // ti, ds-write tile ti+1, barrier.
    ISSUE_OUT(ldA, 2); MFMA_OUT(0); WRITE_OUT(ldB, 1); __syncthreads();
    ISSUE_OUT(ldB, 3); MFMA_OUT(1); WRITE_OUT(ldA, 2); __syncthreads();
    ISSUE_OUT(ldA, 4); MFMA_OUT(2); WRITE_OUT(ldB, 3); __syncthreads();
                       MFMA_OUT(3); WRITE_OUT(ldA, 4); __syncthreads();
                       MFMA_OUT(4);
#undef ISSUE_OUT
#undef WRITE_OUT
#undef MFMA_OUT
}

extern "C" void kernel_launch(void* const* d_in, const int* in_sizes, int n_in,
                              void* d_out, int out_size, void* d_ws, size_t ws_size,
                              hipStream_t stream) {
    const float* x     = (const float*)d_in[0];
    const float* mass  = (const float*)d_in[1];
    const float* evals = (const float*)d_in[2];
    const float* evecs = (const float*)d_in[3];
    const float* dt    = (const float*)d_in[4];
    // d_in[5] = batch (unused: equal-sized graphs), d_in[6] = bs (compile-time 8)
    float* out = (float*)d_out;

    // partials live in the OUTPUT buffer (64MB <= 82MB), fully overwritten by
    // k_out afterwards; Yt lives in the workspace (256KB)
    float* scr = out;
    short* Yt  = (short*)d_ws;

    k_spec<<<NCH * BGR, 256, 0, stream>>>(x, mass, evecs, scr);
    k_coef<<<(BGR * ND * NK) / 256, 256, 0, stream>>>(scr, evals, dt, Yt);
    k_out<<<NBLK * BGR, 256, 0, stream>>>(evecs, Yt, out);
}